// Round 16
// baseline (388.535 us; speedup 1.0000x reference)
//
#include <hip/hip_runtime.h>
#include <hip/hip_bf16.h>

#define BB 2
#define SS 2048
#define DD 256
#define HH 8
#define DKK 32
#define DVV 32
#define LL 3

typedef __hip_bfloat16 bf16;
typedef __attribute__((ext_vector_type(8))) short bfrag;
typedef __attribute__((ext_vector_type(4))) float f4;

struct alignas(8) bh4 { bf16 a, b, c, d; };

__device__ __forceinline__ bfrag ld8(const bf16* p) {
  return *reinterpret_cast<const bfrag*>(p);
}

// ---------------- weight transpose + cast: wts[l][t][n][k] = W_t[l][k][n] ----------------
__global__ __launch_bounds__(256) void cast_weights_k(const float* __restrict__ wq,
                                                      const float* __restrict__ wk,
                                                      const float* __restrict__ wv,
                                                      const float* __restrict__ wfc,
                                                      bf16* __restrict__ wts) {
  int e = blockIdx.x * 256 + threadIdx.x;   // 786432 total
  int mat = e >> 16;                        // 0..11 = l*4 + t
  int t = mat & 3;
  int l = mat >> 2;
  int kk = (e >> 8) & 255;
  int n = e & 255;
  const float* src = (t == 0) ? wq : (t == 1) ? wk : (t == 2) ? wv : wfc;
  float v = src[((size_t)l * 256 + kk) * 256 + n];
  wts[(size_t)mat * 65536 + (size_t)n * 256 + kk] = __float2bfloat16(v);
}

// ---------------- x = seq + positional encoding, cast bf16 ----------------
__global__ __launch_bounds__(256) void pe_add_k(const float* __restrict__ seq,
                                                bf16* __restrict__ xbf) {
  int e = blockIdx.x * 256 + threadIdx.x;   // 1,048,576 total
  int d = e & 255;
  int m = e >> 8;
  int s = m & (SS - 1);
  int i2 = d >> 1;
  float div = __expf((float)(2 * i2) * (-9.210340371976184f / 256.0f));
  float ang = (float)s * div;
  float pe = (d & 1) ? __cosf(ang) : __sinf(ang);
  xbf[e] = __float2bfloat16(seq[e] + pe);
}

// ---------------- Q/K/V projection GEMM: [4096,256] @ [256,256]x3 ----------------
__global__ __launch_bounds__(256) void proj_k(const bf16* __restrict__ xbf,
                                              const bf16* __restrict__ wl,
                                              bf16* __restrict__ q,
                                              bf16* __restrict__ k,
                                              bf16* __restrict__ vt) {
  int lane = threadIdx.x & 63;
  int wv = threadIdx.x >> 6;
  int c = lane & 15, g = lane >> 4;
  int t = blockIdx.y >> 2;
  int n0 = (blockIdx.y & 3) * 64;
  int m0 = blockIdx.x * 64 + wv * 16;
  const bf16* wt = wl + (size_t)t * 65536;
  const bf16* arow = xbf + (size_t)(m0 + c) * 256 + g * 8;
  f4 acc[4];
#pragma unroll
  for (int i = 0; i < 4; ++i) acc[i] = (f4){0.f, 0.f, 0.f, 0.f};
#pragma unroll
  for (int kk = 0; kk < 8; ++kk) {
    bfrag af = ld8(arow + kk * 32);
#pragma unroll
    for (int ns = 0; ns < 4; ++ns) {
      bfrag bfr = ld8(wt + (size_t)(n0 + ns * 16 + c) * 256 + kk * 32 + g * 8);
      acc[ns] = __builtin_amdgcn_mfma_f32_16x16x32_bf16(af, bfr, acc[ns], 0, 0, 0);
    }
  }
#pragma unroll
  for (int ns = 0; ns < 4; ++ns) {
#pragma unroll
    for (int r = 0; r < 4; ++r) {
      int m = m0 + g * 4 + r;
      int n = n0 + ns * 16 + c;
      int b = m >> 11, s = m & (SS - 1);
      int h = n >> 5, d = n & 31;
      bf16 v = __float2bfloat16(acc[ns][r]);
      if (t == 0)      q[((size_t)(b * HH + h) * SS + s) * DKK + d] = v;
      else if (t == 1) k[((size_t)(b * HH + h) * SS + s) * DKK + d] = v;
      else             vt[((size_t)(b * HH + h) * DVV + d) * SS + s] = v;  // V transposed
    }
  }
}

// ---------------- FC GEMM: ctx[4096,256] @ Wfc[256,256] ----------------
__global__ __launch_bounds__(256) void fc_k(const bf16* __restrict__ ctxbf,
                                            const bf16* __restrict__ wt,
                                            bf16* __restrict__ xbf,
                                            float* __restrict__ fout, int wf) {
  int lane = threadIdx.x & 63;
  int wv = threadIdx.x >> 6;
  int c = lane & 15, g = lane >> 4;
  int n0 = blockIdx.y * 64;
  int m0 = blockIdx.x * 64 + wv * 16;
  const bf16* arow = ctxbf + (size_t)(m0 + c) * 256 + g * 8;
  f4 acc[4];
#pragma unroll
  for (int i = 0; i < 4; ++i) acc[i] = (f4){0.f, 0.f, 0.f, 0.f};
#pragma unroll
  for (int kk = 0; kk < 8; ++kk) {
    bfrag af = ld8(arow + kk * 32);
#pragma unroll
    for (int ns = 0; ns < 4; ++ns) {
      bfrag bfr = ld8(wt + (size_t)(n0 + ns * 16 + c) * 256 + kk * 32 + g * 8);
      acc[ns] = __builtin_amdgcn_mfma_f32_16x16x32_bf16(af, bfr, acc[ns], 0, 0, 0);
    }
  }
#pragma unroll
  for (int ns = 0; ns < 4; ++ns) {
#pragma unroll
    for (int r = 0; r < 4; ++r) {
      int m = m0 + g * 4 + r;
      int n = n0 + ns * 16 + c;
      float v = acc[ns][r];
      xbf[(size_t)m * 256 + n] = __float2bfloat16(v);
      if (wf) fout[(size_t)m * 256 + n] = v;
    }
  }
}

// ---------------- ctx partial combine: ctxbf = bf16(ctxp0 + ctxp1) ----------------
__global__ __launch_bounds__(256) void combine_ctx_k(const float* __restrict__ p0,
                                                     const float* __restrict__ p1,
                                                     bf16* __restrict__ o) {
  int e = (blockIdx.x * 256 + threadIdx.x) * 4;   // 1,048,576 elems / 4
  f4 a = *reinterpret_cast<const f4*>(p0 + e);
  f4 b = *reinterpret_cast<const f4*>(p1 + e);
  bh4 w = {__float2bfloat16(a[0] + b[0]), __float2bfloat16(a[1] + b[1]),
           __float2bfloat16(a[2] + b[2]), __float2bfloat16(a[3] + b[3])};
  *reinterpret_cast<bh4*>(o + e) = w;
}

// ---------------- FUSED attention, K-SPLIT x2 (TLP-vs-BW discriminator) ----------
// grid (SS/64, B*H, 2): z splits pass2's k-columns in half -> 1024 independent
// blocks = 4 blocks/CU = 4 waves/SIMD (2x TLP vs R11/R15). Pass 1 (row sums over
// FULL K) duplicated per z-half: 2x work, 2x parallelism -> wall-neutral. PV
// partials to per-z fp32 buffers (contiguous, selected by blockIdx.z), summed by
// combine_ctx_k. aout column-ranges disjoint by z.
__global__ __launch_bounds__(256) void attn_full_k(const bf16* __restrict__ q,
                                                   const bf16* __restrict__ k,
                                                   const bf16* __restrict__ vt,
                                                   float* __restrict__ aout,
                                                   float* __restrict__ ctxp) {
  const float C2 = 0.2550350812540738f;  // log2(e)/sqrt(32)
  int lane = threadIdx.x & 63;
  int wv = threadIdx.x >> 6;
  int c = lane & 15, g = lane >> 4;
  int bh = blockIdx.y;
  int b = bh >> 3, h = bh & 7;
  int s0 = blockIdx.x * 64 + wv * 16;
  int jbase = blockIdx.z * (SS / 128);   // 16 chunks of 64 cols per z-half
  ctxp += (size_t)blockIdx.z * ((size_t)BB * SS * DD);   // select partial buffer
  const bf16* qb = q + ((size_t)bh * SS + s0) * DKK;
  const bf16* kb = k + (size_t)bh * SS * DKK;
  const bf16* vb = vt + (size_t)bh * DVV * SS;
  bfrag qf = ld8(qb + c * DKK + g * 8);
  const f4 z = {0.f, 0.f, 0.f, 0.f};

  // ---- pass 1: row sums of exp(s) over FULL K; lane-local via swapped MFMA ----
  float sum = 0.f;
#pragma unroll 4
  for (int kc = 0; kc < SS / 16; ++kc) {
    bfrag kf = ld8(kb + (size_t)(kc * 16 + c) * DKK + g * 8);
    f4 sc = __builtin_amdgcn_mfma_f32_16x16x32_bf16(kf, qf, z, 0, 0, 0);
#pragma unroll
    for (int r = 0; r < 4; ++r) sum += __builtin_amdgcn_exp2f(sc[r] * C2);
  }
  sum += __shfl_xor(sum, 16, 64);
  sum += __shfl_xor(sum, 32, 64);
  float inv = 1.0f / sum;   // lane (c,*) holds inv for q-row s0+c

  // ---- pass 2: this z-half's 16 chunks -> {swizzled store tile, bf16 PV tile} ----
  __shared__ __align__(16) float pws[4][16 * 64];   // fp32 store-bounce, swizzled
  __shared__ __align__(16) bf16 pbf[4][16][72];     // bf16 PV tile (64 + 8 pad)
  float* pw = pws[wv];
  float* arow = aout + ((size_t)bh * SS + s0) * SS;
  f4 acc0 = z, acc1 = z;

  for (int jj = 0; jj < SS / 128; ++jj) {
    int j = jbase + jj;
#pragma unroll
    for (int t = 0; t < 4; ++t) {
      bfrag kf = ld8(kb + (size_t)(j * 64 + t * 16 + c) * DKK + g * 8);
      f4 sc = __builtin_amdgcn_mfma_f32_16x16x32_bf16(kf, qf, z, 0, 0, 0);
      f4 p;
#pragma unroll
      for (int r = 0; r < 4; ++r) p[r] = __builtin_amdgcn_exp2f(sc[r] * C2) * inv;
      *reinterpret_cast<f4*>(&pw[c * 64 + (((t * 4 + g) ^ c) << 2)]) = p;
      bh4 w = {__float2bfloat16(p[0]), __float2bfloat16(p[1]),
               __float2bfloat16(p[2]), __float2bfloat16(p[3])};
      *reinterpret_cast<bh4*>(&pbf[wv][c][t * 16 + g * 4]) = w;
    }
#pragma unroll
    for (int ks = 0; ks < 2; ++ks) {
      bfrag pa = ld8(&pbf[wv][c][ks * 32 + g * 8]);
      bfrag vf0 = ld8(vb + (size_t)c * SS + j * 64 + ks * 32 + g * 8);
      acc0 = __builtin_amdgcn_mfma_f32_16x16x32_bf16(pa, vf0, acc0, 0, 0, 0);
      bfrag vf1 = ld8(vb + (size_t)(16 + c) * SS + j * 64 + ks * 32 + g * 8);
      acc1 = __builtin_amdgcn_mfma_f32_16x16x32_bf16(pa, vf1, acc1, 0, 0, 0);
    }
#pragma unroll
    for (int qq = 0; qq < 4; ++qq) {
      int row = qq * 4 + g;
      f4 v = *reinterpret_cast<f4*>(&pw[row * 64 + ((c ^ row) << 2)]);
      *reinterpret_cast<f4*>(&arow[(size_t)row * SS + j * 64 + (c << 2)]) = v;
    }
  }

  // ---- epilogue: fp32 PV partials (normalized) ----
#pragma unroll
  for (int r = 0; r < 4; ++r) {
    int srow = s0 + g * 4 + r;
    size_t base = ((size_t)b * SS + srow) * 256 + h * 32;
    ctxp[base + c] = acc0[r];
    ctxp[base + 16 + c] = acc1[r];
  }
}

extern "C" void kernel_launch(void* const* d_in, const int* in_sizes, int n_in,
                              void* d_out, int out_size, void* d_ws, size_t ws_size,
                              hipStream_t stream) {
  (void)in_sizes; (void)n_in; (void)out_size; (void)ws_size;
  const float* seq = (const float*)d_in[0];
  const float* Wq  = (const float*)d_in[1];
  const float* Wk  = (const float*)d_in[2];
  const float* Wv  = (const float*)d_in[3];
  const float* Wfc = (const float*)d_in[4];
  float* out = (float*)d_out;
  float* attns = out + (size_t)BB * SS * DD;

  const size_t MB2 = 2097152;
  char* ws = (char*)d_ws;
  bf16* wts  = (bf16*)(ws);                        // 1.5 MB
  bf16* xbf  = (bf16*)(ws + 1572864);              // 2 MB
  bf16* vtb  = (bf16*)(ws + 1572864 + MB2);        // 2 MB
  bf16* ctxb = (bf16*)(ws + 1572864 + 2 * MB2);    // 2 MB
  bf16* qb   = (bf16*)(ws + 1572864 + 3 * MB2);    // 2 MB
  bf16* kb   = (bf16*)(ws + 1572864 + 4 * MB2);    // 2 MB
  float* ctxp = (float*)(ws + 1572864 + 5 * MB2);  // 2 x 4 MB (contiguous)

  cast_weights_k<<<3072, 256, 0, stream>>>(Wq, Wk, Wv, Wfc, wts);
  pe_add_k<<<4096, 256, 0, stream>>>(seq, xbf);

  for (int l = 0; l < LL; ++l) {
    proj_k<<<dim3(64, 12), 256, 0, stream>>>(xbf, wts + (size_t)l * 4 * 65536, qb, kb, vtb);
    attn_full_k<<<dim3(SS / 64, BB * HH, 2), 256, 0, stream>>>(
        qb, kb, vtb, attns + (size_t)l * BB * HH * SS * SS, ctxp);
    combine_ctx_k<<<1024, 256, 0, stream>>>(ctxp, ctxp + (size_t)BB * SS * DD, ctxb);
    fc_k<<<dim3(64, 4), 256, 0, stream>>>(ctxb, wts + ((size_t)l * 4 + 3) * 65536,
                                          xbf, out, (l == LL - 1) ? 1 : 0);
  }
}

// Round 17
// 344.441 us; speedup vs baseline: 1.1280x; 1.1280x over previous
//
#include <hip/hip_runtime.h>
#include <hip/hip_bf16.h>

#define BB 2
#define SS 2048
#define DD 256
#define HH 8
#define DKK 32
#define DVV 32
#define LL 3

typedef __hip_bfloat16 bf16;
typedef __attribute__((ext_vector_type(8))) short bfrag;
typedef __attribute__((ext_vector_type(4))) float f4;

struct alignas(8) bh4 { bf16 a, b, c, d; };

__device__ __forceinline__ bfrag ld8(const bf16* p) {
  return *reinterpret_cast<const bfrag*>(p);
}

// ---------------- weight transpose + cast: wts[l][t][n][k] = W_t[l][k][n] ----------------
__global__ __launch_bounds__(256) void cast_weights_k(const float* __restrict__ wq,
                                                      const float* __restrict__ wk,
                                                      const float* __restrict__ wv,
                                                      const float* __restrict__ wfc,
                                                      bf16* __restrict__ wts) {
  int e = blockIdx.x * 256 + threadIdx.x;   // 786432 total
  int mat = e >> 16;                        // 0..11 = l*4 + t
  int t = mat & 3;
  int l = mat >> 2;
  int kk = (e >> 8) & 255;
  int n = e & 255;
  const float* src = (t == 0) ? wq : (t == 1) ? wk : (t == 2) ? wv : wfc;
  float v = src[((size_t)l * 256 + kk) * 256 + n];
  wts[(size_t)mat * 65536 + (size_t)n * 256 + kk] = __float2bfloat16(v);
}

// ---------------- x = seq + positional encoding, cast bf16 ----------------
__global__ __launch_bounds__(256) void pe_add_k(const float* __restrict__ seq,
                                                bf16* __restrict__ xbf) {
  int e = blockIdx.x * 256 + threadIdx.x;   // 1,048,576 total
  int d = e & 255;
  int m = e >> 8;
  int s = m & (SS - 1);
  int i2 = d >> 1;
  float div = __expf((float)(2 * i2) * (-9.210340371976184f / 256.0f));
  float ang = (float)s * div;
  float pe = (d & 1) ? __cosf(ang) : __sinf(ang);
  xbf[e] = __float2bfloat16(seq[e] + pe);
}

// ---------------- Q/K/V projection GEMM: [4096,256] @ [256,256]x3 ----------------
__global__ __launch_bounds__(256) void proj_k(const bf16* __restrict__ xbf,
                                              const bf16* __restrict__ wl,
                                              bf16* __restrict__ q,
                                              bf16* __restrict__ k,
                                              bf16* __restrict__ vt) {
  int lane = threadIdx.x & 63;
  int wv = threadIdx.x >> 6;
  int c = lane & 15, g = lane >> 4;
  int t = blockIdx.y >> 2;
  int n0 = (blockIdx.y & 3) * 64;
  int m0 = blockIdx.x * 64 + wv * 16;
  const bf16* wt = wl + (size_t)t * 65536;
  const bf16* arow = xbf + (size_t)(m0 + c) * 256 + g * 8;
  f4 acc[4];
#pragma unroll
  for (int i = 0; i < 4; ++i) acc[i] = (f4){0.f, 0.f, 0.f, 0.f};
#pragma unroll
  for (int kk = 0; kk < 8; ++kk) {
    bfrag af = ld8(arow + kk * 32);
#pragma unroll
    for (int ns = 0; ns < 4; ++ns) {
      bfrag bfr = ld8(wt + (size_t)(n0 + ns * 16 + c) * 256 + kk * 32 + g * 8);
      acc[ns] = __builtin_amdgcn_mfma_f32_16x16x32_bf16(af, bfr, acc[ns], 0, 0, 0);
    }
  }
#pragma unroll
  for (int ns = 0; ns < 4; ++ns) {
#pragma unroll
    for (int r = 0; r < 4; ++r) {
      int m = m0 + g * 4 + r;
      int n = n0 + ns * 16 + c;
      int b = m >> 11, s = m & (SS - 1);
      int h = n >> 5, d = n & 31;
      bf16 v = __float2bfloat16(acc[ns][r]);
      if (t == 0)      q[((size_t)(b * HH + h) * SS + s) * DKK + d] = v;
      else if (t == 1) k[((size_t)(b * HH + h) * SS + s) * DKK + d] = v;
      else             vt[((size_t)(b * HH + h) * DVV + d) * SS + s] = v;  // V transposed
    }
  }
}

// ---------------- FC GEMM: ctx[4096,256] @ Wfc[256,256] ----------------
__global__ __launch_bounds__(256) void fc_k(const bf16* __restrict__ ctxbf,
                                            const bf16* __restrict__ wt,
                                            bf16* __restrict__ xbf,
                                            float* __restrict__ fout, int wf) {
  int lane = threadIdx.x & 63;
  int wv = threadIdx.x >> 6;
  int c = lane & 15, g = lane >> 4;
  int n0 = blockIdx.y * 64;
  int m0 = blockIdx.x * 64 + wv * 16;
  const bf16* arow = ctxbf + (size_t)(m0 + c) * 256 + g * 8;
  f4 acc[4];
#pragma unroll
  for (int i = 0; i < 4; ++i) acc[i] = (f4){0.f, 0.f, 0.f, 0.f};
#pragma unroll
  for (int kk = 0; kk < 8; ++kk) {
    bfrag af = ld8(arow + kk * 32);
#pragma unroll
    for (int ns = 0; ns < 4; ++ns) {
      bfrag bfr = ld8(wt + (size_t)(n0 + ns * 16 + c) * 256 + kk * 32 + g * 8);
      acc[ns] = __builtin_amdgcn_mfma_f32_16x16x32_bf16(af, bfr, acc[ns], 0, 0, 0);
    }
  }
#pragma unroll
  for (int ns = 0; ns < 4; ++ns) {
#pragma unroll
    for (int r = 0; r < 4; ++r) {
      int m = m0 + g * 4 + r;
      int n = n0 + ns * 16 + c;
      float v = acc[ns][r];
      xbf[(size_t)m * 256 + n] = __float2bfloat16(v);
      if (wf) fout[(size_t)m * 256 + n] = v;
    }
  }
}

// ---------------- FUSED attention (R15 form — measured best, 342.7 us) ----------
// mfma(K,Q): lane (c,g) reg r = S[q-row c][k-col g*4+r] -> 4 consecutive k-cols
// per lane. pass1 sums lane-local (1 acc, 2 shfl_xor); pass2 LDS bounce is
// 1 ds_write_b128 (pws) + 1 ds_write_b64 (pbf) per tile. pws XOR layout is an
// involution; drain = 4x256B-contiguous dwordx4/chunk; PV hides under drain.
__global__ __launch_bounds__(256) void attn_full_k(const bf16* __restrict__ q,
                                                   const bf16* __restrict__ k,
                                                   const bf16* __restrict__ vt,
                                                   float* __restrict__ aout,
                                                   bf16* __restrict__ ctxbf) {
  const float C2 = 0.2550350812540738f;  // log2(e)/sqrt(32)
  int lane = threadIdx.x & 63;
  int wv = threadIdx.x >> 6;
  int c = lane & 15, g = lane >> 4;
  int bh = blockIdx.y;
  int b = bh >> 3, h = bh & 7;
  int s0 = blockIdx.x * 64 + wv * 16;
  const bf16* qb = q + ((size_t)bh * SS + s0) * DKK;
  const bf16* kb = k + (size_t)bh * SS * DKK;
  const bf16* vb = vt + (size_t)bh * DVV * SS;
  bfrag qf = ld8(qb + c * DKK + g * 8);
  const f4 z = {0.f, 0.f, 0.f, 0.f};

  // ---- pass 1: row sums of exp(s); swapped MFMA -> lane-local accumulation ----
  float sum = 0.f;
#pragma unroll 4
  for (int kc = 0; kc < SS / 16; ++kc) {
    bfrag kf = ld8(kb + (size_t)(kc * 16 + c) * DKK + g * 8);
    f4 sc = __builtin_amdgcn_mfma_f32_16x16x32_bf16(kf, qf, z, 0, 0, 0);
#pragma unroll
    for (int r = 0; r < 4; ++r) sum += __builtin_amdgcn_exp2f(sc[r] * C2);
  }
  sum += __shfl_xor(sum, 16, 64);
  sum += __shfl_xor(sum, 32, 64);
  float inv = 1.0f / sum;   // lane (c,*) holds inv for q-row s0+c

  // ---- pass 2: recompute -> {swizzled fp32 store tile, bf16 PV tile} ----
  __shared__ __align__(16) float pws[4][16 * 64];   // fp32 store-bounce, swizzled
  __shared__ __align__(16) bf16 pbf[4][16][72];     // bf16 PV tile (64 + 8 pad)
  float* pw = pws[wv];
  float* arow = aout + ((size_t)bh * SS + s0) * SS;
  f4 acc0 = z, acc1 = z;

  for (int j = 0; j < SS / 64; ++j) {
#pragma unroll
    for (int t = 0; t < 4; ++t) {
      bfrag kf = ld8(kb + (size_t)(j * 64 + t * 16 + c) * DKK + g * 8);
      f4 sc = __builtin_amdgcn_mfma_f32_16x16x32_bf16(kf, qf, z, 0, 0, 0);
      f4 p;
#pragma unroll
      for (int r = 0; r < 4; ++r) p[r] = __builtin_amdgcn_exp2f(sc[r] * C2) * inv;
      // pws: row c, col4 = t*4+g stored at (t*4+g)^c  (XOR involution)
      *reinterpret_cast<f4*>(&pw[c * 64 + (((t * 4 + g) ^ c) << 2)]) = p;
      // pbf: row c, cols t*16+g*4 .. +3, one 8B write
      bh4 w = {__float2bfloat16(p[0]), __float2bfloat16(p[1]),
               __float2bfloat16(p[2]), __float2bfloat16(p[3])};
      *reinterpret_cast<bh4*>(&pbf[wv][c][t * 16 + g * 4]) = w;
    }
    // PV: 2 k-slices, A = P rows from pbf, B = V^T rows
#pragma unroll
    for (int ks = 0; ks < 2; ++ks) {
      bfrag pa = ld8(&pbf[wv][c][ks * 32 + g * 8]);
      bfrag vf0 = ld8(vb + (size_t)c * SS + j * 64 + ks * 32 + g * 8);
      acc0 = __builtin_amdgcn_mfma_f32_16x16x32_bf16(pa, vf0, acc0, 0, 0, 0);
      bfrag vf1 = ld8(vb + (size_t)(16 + c) * SS + j * 64 + ks * 32 + g * 8);
      acc1 = __builtin_amdgcn_mfma_f32_16x16x32_bf16(pa, vf1, acc1, 0, 0, 0);
    }
    // drain: 4 x 256B-contiguous dwordx4
#pragma unroll
    for (int qq = 0; qq < 4; ++qq) {
      int row = qq * 4 + g;
      f4 v = *reinterpret_cast<f4*>(&pw[row * 64 + ((c ^ row) << 2)]);
      *reinterpret_cast<f4*>(&arow[(size_t)row * SS + j * 64 + (c << 2)]) = v;
    }
  }

  // ---- epilogue: ctx (already normalized) ----
#pragma unroll
  for (int r = 0; r < 4; ++r) {
    int srow = s0 + g * 4 + r;
    size_t base = ((size_t)b * SS + srow) * 256 + h * 32;
    ctxbf[base + c] = __float2bfloat16(acc0[r]);
    ctxbf[base + 16 + c] = __float2bfloat16(acc1[r]);
  }
}

extern "C" void kernel_launch(void* const* d_in, const int* in_sizes, int n_in,
                              void* d_out, int out_size, void* d_ws, size_t ws_size,
                              hipStream_t stream) {
  (void)in_sizes; (void)n_in; (void)out_size; (void)ws_size;
  const float* seq = (const float*)d_in[0];
  const float* Wq  = (const float*)d_in[1];
  const float* Wk  = (const float*)d_in[2];
  const float* Wv  = (const float*)d_in[3];
  const float* Wfc = (const float*)d_in[4];
  float* out = (float*)d_out;
  float* attns = out + (size_t)BB * SS * DD;

  const size_t MB2 = 2097152;
  char* ws = (char*)d_ws;
  bf16* wts  = (bf16*)(ws);                       // 1.5 MB
  bf16* xbf  = (bf16*)(ws + 1572864);             // 2 MB
  bf16* vtb  = (bf16*)(ws + 1572864 + MB2);       // 2 MB
  bf16* ctxb = (bf16*)(ws + 1572864 + 2 * MB2);   // 2 MB
  bf16* qb   = (bf16*)(ws + 1572864 + 3 * MB2);   // 2 MB
  bf16* kb   = (bf16*)(ws + 1572864 + 4 * MB2);   // 2 MB

  cast_weights_k<<<3072, 256, 0, stream>>>(Wq, Wk, Wv, Wfc, wts);
  pe_add_k<<<4096, 256, 0, stream>>>(seq, xbf);

  for (int l = 0; l < LL; ++l) {
    proj_k<<<dim3(64, 12), 256, 0, stream>>>(xbf, wts + (size_t)l * 4 * 65536, qb, kb, vtb);
    attn_full_k<<<dim3(SS / 64, BB * HH), 256, 0, stream>>>(
        qb, kb, vtb, attns + (size_t)l * BB * HH * SS * SS, ctxb);
    fc_k<<<dim3(64, 4), 256, 0, stream>>>(ctxb, wts + ((size_t)l * 4 + 3) * 65536,
                                          xbf, out, (l == LL - 1) ? 1 : 0);
  }
}